// Round 6
// baseline (398.294 us; speedup 1.0000x reference)
//
#include <hip/hip_runtime.h>
#include <hip/hip_fp16.h>

#define HD 128      // hidden dim
#define CHUNK 4096  // edges per coarse-sort block
#define MAXNB 512   // max coarse buckets (N/256; N=100K -> 391)

// ---- src out-degree, 4-replica, 4 edges/thread ----
__global__ __launch_bounds__(256) void count_src4(const int* __restrict__ src,
                                                  unsigned int* __restrict__ cnt4s,
                                                  int N, int E) {
    int t = blockIdx.x * 256 + threadIdx.x;
    int e0 = t * 4;
    if (e0 >= E) return;
    if (e0 + 3 < E) {
        int4 s4 = ((const int4*)src)[t];
        atomicAdd(&cnt4s[0 * N + s4.x], 1u);
        atomicAdd(&cnt4s[1 * N + s4.y], 1u);
        atomicAdd(&cnt4s[2 * N + s4.z], 1u);
        atomicAdd(&cnt4s[3 * N + s4.w], 1u);
    } else {
        for (int j = 0; e0 + j < E; ++j)
            atomicAdd(&cnt4s[j * N + src[e0 + j]], 1u);
    }
}

__global__ __launch_bounds__(256) void make_norm_src(const unsigned int* __restrict__ cnt4s,
                                                     float* __restrict__ norm_src, int N) {
    int i = blockIdx.x * 256 + threadIdx.x;
    if (i < N) {
        float od = (float)(cnt4s[i] + cnt4s[N + i] + cnt4s[2 * N + i] + cnt4s[3 * N + i]);
        norm_src[i] = rsqrtf(od > 1.f ? od : 1.f);
    }
}

// ---- coarse histogram: per-chunk LDS hist of dst>>8, bucket-major output ----
__global__ __launch_bounds__(256) void hist_coarse(const int* __restrict__ dst,
                                                   unsigned int* __restrict__ gHist,
                                                   int NB, int NC, int E) {
    __shared__ unsigned int hist[MAXNB];
    for (int b = threadIdx.x; b < NB; b += 256) hist[b] = 0;
    __syncthreads();
    int chunk = blockIdx.x;
    int base = chunk * CHUNK;
    int end = base + CHUNK < E ? base + CHUNK : E;
    for (int e = base + threadIdx.x; e < end; e += 256)
        atomicAdd(&hist[dst[e] >> 8], 1u);
    __syncthreads();
    for (int b = threadIdx.x; b < NB; b += 256)
        gHist[(size_t)b * NC + chunk] = hist[b];
}

// ---- 3-phase exclusive scan (generic length) ----
__global__ __launch_bounds__(256) void scan_a(const unsigned int* __restrict__ cnt,
                                              unsigned int* __restrict__ excl,
                                              unsigned int* __restrict__ bsum, int n) {
    int i = blockIdx.x * 256 + threadIdx.x;
    unsigned int v = (i < n) ? cnt[i] : 0u;
    unsigned int x = v;
#pragma unroll
    for (int d = 1; d < 64; d <<= 1) {
        unsigned int y = __shfl_up(x, d, 64);
        if ((threadIdx.x & 63) >= d) x += y;
    }
    __shared__ unsigned int wsum[4];
    if ((threadIdx.x & 63) == 63) wsum[threadIdx.x >> 6] = x;
    __syncthreads();
    unsigned int woff = 0;
    for (int w = 0; w < (int)(threadIdx.x >> 6); ++w) woff += wsum[w];
    unsigned int incl = x + woff;
    if (i < n) excl[i] = incl - v;
    if (threadIdx.x == 255) bsum[blockIdx.x] = incl;
}

__global__ __launch_bounds__(1024) void scan_b(const unsigned int* __restrict__ bsum,
                                               unsigned int* __restrict__ boff, int nb) {
    int t = threadIdx.x;
    unsigned int v = (t < nb) ? bsum[t] : 0u;
    unsigned int x = v;
#pragma unroll
    for (int d = 1; d < 64; d <<= 1) {
        unsigned int y = __shfl_up(x, d, 64);
        if ((t & 63) >= d) x += y;
    }
    __shared__ unsigned int wsum[16];
    if ((t & 63) == 63) wsum[t >> 6] = x;
    __syncthreads();
    unsigned int woff = 0;
    for (int w = 0; w < (t >> 6); ++w) woff += wsum[w];
    unsigned int incl = x + woff;
    if (t < nb) boff[t] = incl - v;
}

__global__ __launch_bounds__(256) void scan_c(unsigned int* __restrict__ excl,
                                              const unsigned int* __restrict__ boff, int n) {
    int i = blockIdx.x * 256 + threadIdx.x;
    if (i < n) excl[i] += boff[blockIdx.x];
}

// ---- coarse scatter: pack (dst&255)<<24 | src into bucket-contiguous runs ----
__global__ __launch_bounds__(256) void scatter_coarse(const int* __restrict__ src,
                                                      const int* __restrict__ dst,
                                                      const unsigned int* __restrict__ scanA,
                                                      unsigned int* __restrict__ packed,
                                                      int NB, int NC, int E) {
    __shared__ unsigned int curs[MAXNB];
    int chunk = blockIdx.x;
    for (int b = threadIdx.x; b < NB; b += 256)
        curs[b] = scanA[(size_t)b * NC + chunk];
    __syncthreads();
    int base = chunk * CHUNK;
    int end = base + CHUNK < E ? base + CHUNK : E;
    for (int e = base + threadIdx.x; e < end; e += 256) {
        int d = dst[e];
        int s = src[e];
        unsigned int pos = atomicAdd(&curs[d >> 8], 1u);
        packed[pos] = ((unsigned int)(d & 255) << 24) | (unsigned int)s;
    }
}

// ---- fine sort within each bucket + emit offsets/cnt/norm_dst ----
__global__ __launch_bounds__(256) void fine_sort(const unsigned int* __restrict__ packed,
                                                 const unsigned int* __restrict__ scanA,
                                                 int* __restrict__ sorted_src,
                                                 unsigned int* __restrict__ offsets,
                                                 unsigned int* __restrict__ cntg,
                                                 float* __restrict__ normd,
                                                 int NB, int NC, int N, int E) {
    __shared__ unsigned int cnt[256];
    __shared__ unsigned int curs[256];
    __shared__ unsigned int wsum[4];
    int b = blockIdx.x;
    int t = threadIdx.x;
    unsigned int S = scanA[(size_t)b * NC];
    unsigned int T = (b + 1 < NB) ? scanA[(size_t)(b + 1) * NC] : (unsigned int)E;
    cnt[t] = 0;
    __syncthreads();
    for (unsigned int j = S + t; j < T; j += 256)
        atomicAdd(&cnt[packed[j] >> 24], 1u);
    __syncthreads();
    unsigned int v = cnt[t], x = v;
    int lane = t & 63;
#pragma unroll
    for (int d = 1; d < 64; d <<= 1) {
        unsigned int y = __shfl_up(x, d, 64);
        if (lane >= d) x += y;
    }
    if (lane == 63) wsum[t >> 6] = x;
    __syncthreads();
    unsigned int woff = 0;
    for (int w = 0; w < (t >> 6); ++w) woff += wsum[w];
    unsigned int ex = x - v + woff;
    curs[t] = ex;
    int node = b * 256 + t;
    if (node < N) {
        offsets[node] = S + ex;
        cntg[node] = v;
        float f = (float)v;
        normd[node] = rsqrtf(f > 1.f ? f : 1.f);
    }
    __syncthreads();
    for (unsigned int j = S + t; j < T; j += 256) {
        unsigned int p = packed[j];
        unsigned int pos = S + atomicAdd(&curs[p >> 24], 1u);
        sorted_src[pos] = (int)(p & 0xFFFFFFu);
    }
}

// ---- xh = fp16(x * norm_src) ----
__global__ __launch_bounds__(256) void prep_x(const float* __restrict__ x,
                                              const float* __restrict__ norm,
                                              __half* __restrict__ xh, int total) {
    int t = blockIdx.x * 256 + threadIdx.x;   // one float4 per thread
    if (t >= total) return;
    int row = t >> 5;
    float nr = norm[row];
    float4 v = ((const float4*)x)[t];
    __half2 lo = __floats2half2_rn(v.x * nr, v.y * nr);
    __half2 hi = __floats2half2_rn(v.z * nr, v.w * nr);
    uint2 pk;
    pk.x = *(unsigned int*)&lo;
    pk.y = *(unsigned int*)&hi;
    ((uint2*)xh)[t] = pk;
}

// ---- h = xh @ W, fp16 in/out, W converted to fp16 LDS, 8-row register blocking ----
// 256 threads = 8 groups x 32 lanes; group g -> rows g*8..g*8+7; block = 64 rows.
__global__ __launch_bounds__(256) void gemm_h(const __half* __restrict__ xh,
                                              const float* __restrict__ W,
                                              __half* __restrict__ h, int n) {
    __shared__ __half2 Wh[HD * 64];   // [k][64 half2] = 32 KB
    __shared__ float  xs[64][HD];     // 32 KB
    const int tid = threadIdx.x;

    // stage W -> fp16 LDS: thread covers 16 float4 (=8 half2 each pair)
    {
        const float4* W4 = (const float4*)W;
#pragma unroll
        for (int i = 0; i < 16; ++i) {
            int idx = tid + 256 * i;          // float4 index: k = idx>>5, c4 = idx&31
            float4 wv = W4[idx];
            __half2 a = __floats2half2_rn(wv.x, wv.y);
            __half2 b = __floats2half2_rn(wv.z, wv.w);
            int k = idx >> 5, c4 = idx & 31;
            Wh[k * 64 + c4 * 2]     = a;
            Wh[k * 64 + c4 * 2 + 1] = b;
        }
    }
    const int row0 = blockIdx.x * 64;
    // stage xh -> f32 LDS: 2048 uint2 (4 halves each)
    {
#pragma unroll
        for (int i = 0; i < 8; ++i) {
            int idx = i * 256 + tid;          // uint2 index: row = idx>>5, c = idx&31
            int r = idx >> 5, c = idx & 31;
            int row = row0 + r;
            uint2 u = make_uint2(0u, 0u);
            if (row < n) u = ((const uint2*)xh)[(size_t)row * 32 + c];
            float2 f0 = __half22float2(*(const __half2*)&u.x);
            float2 f1 = __half22float2(*(const __half2*)&u.y);
            ((float4*)xs[r])[c] = make_float4(f0.x, f0.y, f1.x, f1.y);
        }
    }
    __syncthreads();

    const int g  = tid >> 5;   // 8 groups, 8 rows each
    const int c4 = tid & 31;   // float4 output column

    float4 acc[8];
#pragma unroll
    for (int j = 0; j < 8; ++j) acc[j] = make_float4(0.f, 0.f, 0.f, 0.f);

    for (int k = 0; k < HD; k += 2) {
        uint2 w0 = *(const uint2*)&Wh[k * 64 + c4 * 2];
        uint2 w1 = *(const uint2*)&Wh[(k + 1) * 64 + c4 * 2];
        float2 wa0 = __half22float2(*(const __half2*)&w0.x);
        float2 wb0 = __half22float2(*(const __half2*)&w0.y);
        float2 wa1 = __half22float2(*(const __half2*)&w1.x);
        float2 wb1 = __half22float2(*(const __half2*)&w1.y);
#pragma unroll
        for (int j = 0; j < 8; ++j) {
            float2 xk = *(const float2*)&xs[g * 8 + j][k];
            acc[j].x = fmaf(xk.x, wa0.x, acc[j].x);
            acc[j].y = fmaf(xk.x, wa0.y, acc[j].y);
            acc[j].z = fmaf(xk.x, wb0.x, acc[j].z);
            acc[j].w = fmaf(xk.x, wb0.y, acc[j].w);
            acc[j].x = fmaf(xk.y, wa1.x, acc[j].x);
            acc[j].y = fmaf(xk.y, wa1.y, acc[j].y);
            acc[j].z = fmaf(xk.y, wb1.x, acc[j].z);
            acc[j].w = fmaf(xk.y, wb1.y, acc[j].w);
        }
    }

#pragma unroll
    for (int j = 0; j < 8; ++j) {
        int row = row0 + g * 8 + j;
        if (row < n) {
            __half2 lo = __floats2half2_rn(acc[j].x, acc[j].y);
            __half2 hi = __floats2half2_rn(acc[j].z, acc[j].w);
            uint2 pk;
            pk.x = *(unsigned int*)&lo;
            pk.y = *(unsigned int*)&hi;
            ((uint2*)(h + (size_t)row * HD))[c4] = pk;
        }
    }
}

// ---- fused gather-aggregate: wave/node, 4 edges/round x 16B/lane, 16-edge unroll ----
// MID: write fp16 with norm_src folded (input to next gemm). else: fp32 final out.
template <bool MID>
__global__ __launch_bounds__(256) void aggregate_k(const __half* __restrict__ h,
                                                   const int* __restrict__ sorted_src,
                                                   const unsigned int* __restrict__ offsets,
                                                   const unsigned int* __restrict__ cnt,
                                                   const float* __restrict__ norm_dst,
                                                   const float* __restrict__ nsrc,
                                                   const float* __restrict__ bias,
                                                   float* __restrict__ outF,
                                                   __half* __restrict__ outH, int n) {
    int node = blockIdx.x * 4 + (int)(threadIdx.x >> 6);
    if (node >= n) return;
    int lane = threadIdx.x & 63;
    int g   = lane >> 4;    // edge slot 0..3
    int sub = lane & 15;    // 16B slice of the 256B row

    unsigned int start = offsets[node];
    unsigned int deg   = cnt[node];
    const int* sp = sorted_src + start;
    const uint4* h4 = (const uint4*)h;

    float acc[8];
#pragma unroll
    for (int j = 0; j < 8; ++j) acc[j] = 0.f;

#define ACCUM(u)                                                                  \
    { float2 f;                                                                   \
      f = __half22float2(*(const __half2*)&(u).x); acc[0] += f.x; acc[1] += f.y;  \
      f = __half22float2(*(const __half2*)&(u).y); acc[2] += f.x; acc[3] += f.y;  \
      f = __half22float2(*(const __half2*)&(u).z); acc[4] += f.x; acc[5] += f.y;  \
      f = __half22float2(*(const __half2*)&(u).w); acc[6] += f.x; acc[7] += f.y; }

    unsigned int i = 0;
    for (; i + 16 <= deg; i += 16) {
        int s0 = sp[i + g];
        int s1 = sp[i + 4 + g];
        int s2 = sp[i + 8 + g];
        int s3 = sp[i + 12 + g];
        uint4 u0 = h4[(size_t)s0 * 16 + sub];
        uint4 u1 = h4[(size_t)s1 * 16 + sub];
        uint4 u2 = h4[(size_t)s2 * 16 + sub];
        uint4 u3 = h4[(size_t)s3 * 16 + sub];
        ACCUM(u0);
        ACCUM(u1);
        ACCUM(u2);
        ACCUM(u3);
    }
    for (; i < deg; i += 4) {
        if (i + g < deg) {
            int s = sp[i + g];
            uint4 u = h4[(size_t)s * 16 + sub];
            ACCUM(u);
        }
    }
#undef ACCUM

#pragma unroll
    for (int j = 0; j < 8; ++j) {
        acc[j] += __shfl_xor(acc[j], 16, 64);
        acc[j] += __shfl_xor(acc[j], 32, 64);
    }

    float nd = norm_dst[node];
    int col2 = sub * 4 + g;   // float2 / half2 column index 0..63
    float2 bb = ((const float2*)bias)[col2];
    float vx = fmaxf(fmaf(acc[g * 2 + 0], nd, bb.x), 0.f);
    float vy = fmaxf(fmaf(acc[g * 2 + 1], nd, bb.y), 0.f);
    if (MID) {
        float ns = nsrc[node];
        __half2 p = __floats2half2_rn(vx * ns, vy * ns);
        ((__half2*)outH)[(size_t)node * 64 + col2] = p;
    } else {
        ((float2*)outF)[(size_t)node * 64 + col2] = make_float2(vx, vy);
    }
}

extern "C" void kernel_launch(void* const* d_in, const int* in_sizes, int n_in,
                              void* d_out, int out_size, void* d_ws, size_t ws_size,
                              hipStream_t stream) {
    const float* x   = (const float*)d_in[0];
    const float* W1  = (const float*)d_in[1];
    const float* b1  = (const float*)d_in[2];
    const float* W2  = (const float*)d_in[3];
    const float* b2  = (const float*)d_in[4];
    const int*   src = (const int*)d_in[5];
    const int*   dst = (const int*)d_in[6];

    const int N = in_sizes[0] / HD;
    const int E = in_sizes[5];
    float* out = (float*)d_out;

    const int NB = (N + 255) / 256;              // coarse buckets
    const int NC = (E + CHUNK - 1) / CHUNK;      // chunks
    const int scanLen = NB * NC;
    const int nbS = (scanLen + 255) / 256;       // <=1024
    const int nbN = (N + 255) / 256;

    // workspace layout (4B units)
    float*        norm_src = (float*)d_ws;                    // N
    float*        normd    = norm_src + N;                    // N
    unsigned int* cntg     = (unsigned int*)(normd + N);      // N
    unsigned int* offsets  = cntg + N;                        // N
    unsigned int* cnt4s    = offsets + N;                     // 4N (zeroed)
    unsigned int* gHist    = cnt4s + 4 * N;                   // scanLen
    unsigned int* scanA    = gHist + scanLen;                 // scanLen
    unsigned int* bsum     = scanA + scanLen;                 // 1024
    unsigned int* boff     = bsum + 1024;                     // 1024
    unsigned int* packed   = boff + 1024;                     // E
    int*          sorted   = (int*)(packed + E);              // E
    __half*       h        = (__half*)(sorted + E);           // N*HD fp16
    __half*       xh       = h + (size_t)N * HD;              // N*HD fp16

    // ---- norms + bucket sort (shared by both layers) ----
    hipMemsetAsync(cnt4s, 0, (size_t)4 * N * 4, stream);
    count_src4<<<(E / 4 + 255) / 256, 256, 0, stream>>>(src, cnt4s, N, E);
    make_norm_src<<<nbN, 256, 0, stream>>>(cnt4s, norm_src, N);
    hist_coarse<<<NC, 256, 0, stream>>>(dst, gHist, NB, NC, E);
    scan_a<<<nbS, 256, 0, stream>>>(gHist, scanA, bsum, scanLen);
    scan_b<<<1, 1024, 0, stream>>>(bsum, boff, nbS);
    scan_c<<<nbS, 256, 0, stream>>>(scanA, boff, scanLen);
    scatter_coarse<<<NC, 256, 0, stream>>>(src, dst, scanA, packed, NB, NC, E);
    fine_sort<<<NB, 256, 0, stream>>>(packed, scanA, sorted, offsets, cntg, normd, NB, NC, N, E);

    // ---- layer 1 ----
    prep_x<<<(N * 32 + 255) / 256, 256, 0, stream>>>(x, norm_src, xh, N * 32);
    gemm_h<<<(N + 63) / 64, 256, 0, stream>>>(xh, W1, h, N);
    aggregate_k<true><<<(N + 3) / 4, 256, 0, stream>>>(h, sorted, offsets, cntg, normd,
                                                       norm_src, b1, nullptr, xh, N);

    // ---- layer 2 ----
    gemm_h<<<(N + 63) / 64, 256, 0, stream>>>(xh, W2, h, N);
    aggregate_k<false><<<(N + 3) / 4, 256, 0, stream>>>(h, sorted, offsets, cntg, normd,
                                                        nullptr, b2, out, nullptr, N);
}

// Round 7
// 369.714 us; speedup vs baseline: 1.0773x; 1.0773x over previous
//
#include <hip/hip_runtime.h>
#include <hip/hip_fp16.h>

#define HD 128      // hidden dim
#define CHUNK 4096  // edges per coarse-sort block
#define MAXNB 512   // max coarse buckets (N/256; N=100K -> 391)

typedef _Float16 f16x8 __attribute__((ext_vector_type(8)));
typedef float f32x4 __attribute__((ext_vector_type(4)));

// ---- merged: src out-degree (4-replica global atomics) + coarse dst histogram ----
__global__ __launch_bounds__(256) void hist_count(const int* __restrict__ src,
                                                  const int* __restrict__ dst,
                                                  unsigned int* __restrict__ cnt4s,
                                                  unsigned int* __restrict__ gHist,
                                                  int N, int NB, int NC, int E) {
    __shared__ unsigned int hist[MAXNB];
    for (int b = threadIdx.x; b < NB; b += 256) hist[b] = 0;
    __syncthreads();
    int base = blockIdx.x * CHUNK;
    int e0 = base + 4 * threadIdx.x;
#pragma unroll
    for (int it = 0; it < CHUNK / 1024; ++it, e0 += 1024) {
        if (e0 + 3 < E) {
            int4 s4 = *(const int4*)(src + e0);
            int4 d4 = *(const int4*)(dst + e0);
            atomicAdd(&cnt4s[0 * N + s4.x], 1u);
            atomicAdd(&cnt4s[1 * N + s4.y], 1u);
            atomicAdd(&cnt4s[2 * N + s4.z], 1u);
            atomicAdd(&cnt4s[3 * N + s4.w], 1u);
            atomicAdd(&hist[d4.x >> 8], 1u);
            atomicAdd(&hist[d4.y >> 8], 1u);
            atomicAdd(&hist[d4.z >> 8], 1u);
            atomicAdd(&hist[d4.w >> 8], 1u);
        } else {
            for (int j = 0; j < 4; ++j)
                if (e0 + j < E) {
                    atomicAdd(&cnt4s[j * N + src[e0 + j]], 1u);
                    atomicAdd(&hist[dst[e0 + j] >> 8], 1u);
                }
        }
    }
    __syncthreads();
    for (int b = threadIdx.x; b < NB; b += 256)
        gHist[(size_t)b * NC + blockIdx.x] = hist[b];
}

__global__ __launch_bounds__(256) void make_norm_src(const unsigned int* __restrict__ cnt4s,
                                                     float* __restrict__ norm_src, int N) {
    int i = blockIdx.x * 256 + threadIdx.x;
    if (i < N) {
        float od = (float)(cnt4s[i] + cnt4s[N + i] + cnt4s[2 * N + i] + cnt4s[3 * N + i]);
        norm_src[i] = rsqrtf(od > 1.f ? od : 1.f);
    }
}

// ---- Wt = fp16(W^T) for both layers ----
__global__ __launch_bounds__(256) void prep_w(const float* __restrict__ W1,
                                              const float* __restrict__ W2,
                                              _Float16* __restrict__ Wt) {
    const float* W = blockIdx.x ? W2 : W1;
    _Float16* T = Wt + (size_t)blockIdx.x * HD * HD;
    for (int i = threadIdx.x; i < HD * HD; i += 256) {
        int k = i >> 7, c = i & 127;
        T[c * HD + k] = (_Float16)W[i];
    }
}

// ---- 3-phase exclusive scan (generic length) ----
__global__ __launch_bounds__(256) void scan_a(const unsigned int* __restrict__ cnt,
                                              unsigned int* __restrict__ excl,
                                              unsigned int* __restrict__ bsum, int n) {
    int i = blockIdx.x * 256 + threadIdx.x;
    unsigned int v = (i < n) ? cnt[i] : 0u;
    unsigned int x = v;
#pragma unroll
    for (int d = 1; d < 64; d <<= 1) {
        unsigned int y = __shfl_up(x, d, 64);
        if ((threadIdx.x & 63) >= d) x += y;
    }
    __shared__ unsigned int wsum[4];
    if ((threadIdx.x & 63) == 63) wsum[threadIdx.x >> 6] = x;
    __syncthreads();
    unsigned int woff = 0;
    for (int w = 0; w < (int)(threadIdx.x >> 6); ++w) woff += wsum[w];
    unsigned int incl = x + woff;
    if (i < n) excl[i] = incl - v;
    if (threadIdx.x == 255) bsum[blockIdx.x] = incl;
}

__global__ __launch_bounds__(1024) void scan_b(const unsigned int* __restrict__ bsum,
                                               unsigned int* __restrict__ boff, int nb) {
    int t = threadIdx.x;
    unsigned int v = (t < nb) ? bsum[t] : 0u;
    unsigned int x = v;
#pragma unroll
    for (int d = 1; d < 64; d <<= 1) {
        unsigned int y = __shfl_up(x, d, 64);
        if ((t & 63) >= d) x += y;
    }
    __shared__ unsigned int wsum[16];
    if ((t & 63) == 63) wsum[t >> 6] = x;
    __syncthreads();
    unsigned int woff = 0;
    for (int w = 0; w < (t >> 6); ++w) woff += wsum[w];
    unsigned int incl = x + woff;
    if (t < nb) boff[t] = incl - v;
}

__global__ __launch_bounds__(256) void scan_c(unsigned int* __restrict__ excl,
                                              const unsigned int* __restrict__ boff, int n) {
    int i = blockIdx.x * 256 + threadIdx.x;
    if (i < n) excl[i] += boff[blockIdx.x];
}

// ---- coarse scatter: pack (dst&255)<<24 | src into bucket-contiguous runs ----
__global__ __launch_bounds__(256) void scatter_coarse(const int* __restrict__ src,
                                                      const int* __restrict__ dst,
                                                      const unsigned int* __restrict__ scanA,
                                                      unsigned int* __restrict__ packed,
                                                      int NB, int NC, int E) {
    __shared__ unsigned int curs[MAXNB];
    int chunk = blockIdx.x;
    for (int b = threadIdx.x; b < NB; b += 256)
        curs[b] = scanA[(size_t)b * NC + chunk];
    __syncthreads();
    int base = chunk * CHUNK;
    int end = base + CHUNK < E ? base + CHUNK : E;
    for (int e = base + threadIdx.x; e < end; e += 256) {
        int d = dst[e];
        int s = src[e];
        unsigned int pos = atomicAdd(&curs[d >> 8], 1u);
        packed[pos] = ((unsigned int)(d & 255) << 24) | (unsigned int)s;
    }
}

// ---- fine sort within each bucket + emit offsets/cnt/norm_dst ----
__global__ __launch_bounds__(256) void fine_sort(const unsigned int* __restrict__ packed,
                                                 const unsigned int* __restrict__ scanA,
                                                 int* __restrict__ sorted_src,
                                                 unsigned int* __restrict__ offsets,
                                                 unsigned int* __restrict__ cntg,
                                                 float* __restrict__ normd,
                                                 int NB, int NC, int N, int E) {
    __shared__ unsigned int cnt[256];
    __shared__ unsigned int curs[256];
    __shared__ unsigned int wsum[4];
    int b = blockIdx.x;
    int t = threadIdx.x;
    unsigned int S = scanA[(size_t)b * NC];
    unsigned int T = (b + 1 < NB) ? scanA[(size_t)(b + 1) * NC] : (unsigned int)E;
    cnt[t] = 0;
    __syncthreads();
    for (unsigned int j = S + t; j < T; j += 256)
        atomicAdd(&cnt[packed[j] >> 24], 1u);
    __syncthreads();
    unsigned int v = cnt[t], x = v;
    int lane = t & 63;
#pragma unroll
    for (int d = 1; d < 64; d <<= 1) {
        unsigned int y = __shfl_up(x, d, 64);
        if (lane >= d) x += y;
    }
    if (lane == 63) wsum[t >> 6] = x;
    __syncthreads();
    unsigned int woff = 0;
    for (int w = 0; w < (t >> 6); ++w) woff += wsum[w];
    unsigned int ex = x - v + woff;
    curs[t] = ex;
    int node = b * 256 + t;
    if (node < N) {
        offsets[node] = S + ex;
        cntg[node] = v;
        float f = (float)v;
        normd[node] = rsqrtf(f > 1.f ? f : 1.f);
    }
    __syncthreads();
    for (unsigned int j = S + t; j < T; j += 256) {
        unsigned int p = packed[j];
        unsigned int pos = S + atomicAdd(&curs[p >> 24], 1u);
        sorted_src[pos] = (int)(p & 0xFFFFFFu);
    }
}

// ---- xh = fp16(x * norm_src) ----
__global__ __launch_bounds__(256) void prep_x(const float* __restrict__ x,
                                              const float* __restrict__ norm,
                                              _Float16* __restrict__ xh, int total) {
    int t = blockIdx.x * 256 + threadIdx.x;   // one float4 per thread
    if (t >= total) return;
    int row = t >> 5;
    float nr = norm[row];
    float4 v = ((const float4*)x)[t];
    __half2 lo = __floats2half2_rn(v.x * nr, v.y * nr);
    __half2 hi = __floats2half2_rn(v.z * nr, v.w * nr);
    uint2 pk;
    pk.x = *(unsigned int*)&lo;
    pk.y = *(unsigned int*)&hi;
    ((uint2*)xh)[t] = pk;
}

// ---- h = xh @ W via MFMA, computing h^T fragments: D = Wt_frag x xh_frag ----
// Block 256 = 4 waves; wave w covers rows row0+w*16..+15 (all 128 cols). No LDS.
__global__ __launch_bounds__(256) void gemm_mfma(const _Float16* __restrict__ xh,
                                                 const _Float16* __restrict__ Wt,
                                                 _Float16* __restrict__ h, int n) {
    const int tid = threadIdx.x;
    const int w  = tid >> 6;
    const int l  = tid & 63;
    const int lg = l >> 4;    // lane group 0..3 -> k-chunk (lg*8)
    const int li = l & 15;
    const int m  = blockIdx.x * 64 + w * 16 + li;   // x row / output row

    // B-fragments: xh[m][kk*32 + lg*8 .. +7]
    const _Float16* xrow = xh + (size_t)m * HD + lg * 8;
    f16x8 xf[4];
#pragma unroll
    for (int kk = 0; kk < 4; ++kk)
        xf[kk] = *(const f16x8*)(xrow + kk * 32);

    f32x4 acc[8];
#pragma unroll
    for (int t = 0; t < 8; ++t) acc[t] = (f32x4){0.f, 0.f, 0.f, 0.f};

#pragma unroll
    for (int t = 0; t < 8; ++t) {
        const _Float16* wrow = Wt + (size_t)(t * 16 + li) * HD + lg * 8;
#pragma unroll
        for (int kk = 0; kk < 4; ++kk) {
            f16x8 wf = *(const f16x8*)(wrow + kk * 32);
            acc[t] = __builtin_amdgcn_mfma_f32_16x16x32_f16(wf, xf[kk], acc[t], 0, 0, 0);
        }
    }

    if (m < n) {
        // lane holds h[m][t*16 + lg*4 + r], r=0..3 contiguous
        _Float16* hp = h + (size_t)m * HD + lg * 4;
#pragma unroll
        for (int t = 0; t < 8; ++t) {
            __half2 p0 = __floats2half2_rn(acc[t][0], acc[t][1]);
            __half2 p1 = __floats2half2_rn(acc[t][2], acc[t][3]);
            uint2 pk;
            pk.x = *(unsigned int*)&p0;
            pk.y = *(unsigned int*)&p1;
            *(uint2*)(hp + t * 16) = pk;
        }
    }
}

// ---- fused gather-aggregate: wave/node, 4 edges/round x 16B/lane, 16-edge unroll ----
template <bool MID>
__global__ __launch_bounds__(256) void aggregate_k(const __half* __restrict__ h,
                                                   const int* __restrict__ sorted_src,
                                                   const unsigned int* __restrict__ offsets,
                                                   const unsigned int* __restrict__ cnt,
                                                   const float* __restrict__ norm_dst,
                                                   const float* __restrict__ nsrc,
                                                   const float* __restrict__ bias,
                                                   float* __restrict__ outF,
                                                   __half* __restrict__ outH, int n) {
    int node = blockIdx.x * 4 + (int)(threadIdx.x >> 6);
    if (node >= n) return;
    int lane = threadIdx.x & 63;
    int g   = lane >> 4;    // edge slot 0..3
    int sub = lane & 15;    // 16B slice of the 256B row

    unsigned int start = offsets[node];
    unsigned int deg   = cnt[node];
    const int* sp = sorted_src + start;
    const uint4* h4 = (const uint4*)h;

    float acc[8];
#pragma unroll
    for (int j = 0; j < 8; ++j) acc[j] = 0.f;

#define ACCUM(u)                                                                  \
    { float2 f;                                                                   \
      f = __half22float2(*(const __half2*)&(u).x); acc[0] += f.x; acc[1] += f.y;  \
      f = __half22float2(*(const __half2*)&(u).y); acc[2] += f.x; acc[3] += f.y;  \
      f = __half22float2(*(const __half2*)&(u).z); acc[4] += f.x; acc[5] += f.y;  \
      f = __half22float2(*(const __half2*)&(u).w); acc[6] += f.x; acc[7] += f.y; }

    unsigned int i = 0;
    for (; i + 16 <= deg; i += 16) {
        int s0 = sp[i + g];
        int s1 = sp[i + 4 + g];
        int s2 = sp[i + 8 + g];
        int s3 = sp[i + 12 + g];
        uint4 u0 = h4[(size_t)s0 * 16 + sub];
        uint4 u1 = h4[(size_t)s1 * 16 + sub];
        uint4 u2 = h4[(size_t)s2 * 16 + sub];
        uint4 u3 = h4[(size_t)s3 * 16 + sub];
        ACCUM(u0);
        ACCUM(u1);
        ACCUM(u2);
        ACCUM(u3);
    }
    for (; i < deg; i += 4) {
        if (i + g < deg) {
            int s = sp[i + g];
            uint4 u = h4[(size_t)s * 16 + sub];
            ACCUM(u);
        }
    }
#undef ACCUM

#pragma unroll
    for (int j = 0; j < 8; ++j) {
        acc[j] += __shfl_xor(acc[j], 16, 64);
        acc[j] += __shfl_xor(acc[j], 32, 64);
    }

    float nd = norm_dst[node];
    int col2 = sub * 4 + g;   // float2 / half2 column index 0..63
    float2 bb = ((const float2*)bias)[col2];
    float vx = fmaxf(fmaf(acc[g * 2 + 0], nd, bb.x), 0.f);
    float vy = fmaxf(fmaf(acc[g * 2 + 1], nd, bb.y), 0.f);
    if (MID) {
        float ns = nsrc[node];
        __half2 p = __floats2half2_rn(vx * ns, vy * ns);
        ((__half2*)outH)[(size_t)node * 64 + col2] = p;
    } else {
        ((float2*)outF)[(size_t)node * 64 + col2] = make_float2(vx, vy);
    }
}

extern "C" void kernel_launch(void* const* d_in, const int* in_sizes, int n_in,
                              void* d_out, int out_size, void* d_ws, size_t ws_size,
                              hipStream_t stream) {
    const float* x   = (const float*)d_in[0];
    const float* W1  = (const float*)d_in[1];
    const float* b1  = (const float*)d_in[2];
    const float* W2  = (const float*)d_in[3];
    const float* b2  = (const float*)d_in[4];
    const int*   src = (const int*)d_in[5];
    const int*   dst = (const int*)d_in[6];

    const int N = in_sizes[0] / HD;
    const int E = in_sizes[5];
    float* out = (float*)d_out;

    const int NP = (N + 63) & ~63;               // padded rows for 64-row gemm tiles
    const int NB = (N + 255) / 256;              // coarse buckets
    const int NC = (E + CHUNK - 1) / CHUNK;      // chunks
    const int scanLen = NB * NC;
    const int nbS = (scanLen + 255) / 256;       // <=1024
    const int nbN = (N + 255) / 256;

    // workspace layout (4B units)
    float*        norm_src = (float*)d_ws;                    // N
    float*        normd    = norm_src + N;                    // N
    unsigned int* cntg     = (unsigned int*)(normd + N);      // N
    unsigned int* offsets  = cntg + N;                        // N
    unsigned int* cnt4s    = offsets + N;                     // 4N (zeroed)
    unsigned int* gHist    = cnt4s + 4 * N;                   // scanLen
    unsigned int* scanA    = gHist + scanLen;                 // scanLen
    unsigned int* bsum     = scanA + scanLen;                 // 1024
    unsigned int* boff     = bsum + 1024;                     // 1024
    unsigned int* packed   = boff + 1024;                     // E
    int*          sorted   = (int*)(packed + E);              // E
    _Float16*     h        = (_Float16*)(sorted + E);         // NP*HD fp16
    _Float16*     xh       = h + (size_t)NP * HD;             // NP*HD fp16
    _Float16*     Wt       = xh + (size_t)NP * HD;            // 2*HD*HD fp16

    // ---- norms + weight transpose + bucket sort (shared by both layers) ----
    hipMemsetAsync(cnt4s, 0, (size_t)4 * N * 4, stream);
    prep_w<<<2, 256, 0, stream>>>(W1, W2, Wt);
    hist_count<<<NC, 256, 0, stream>>>(src, dst, cnt4s, gHist, N, NB, NC, E);
    make_norm_src<<<nbN, 256, 0, stream>>>(cnt4s, norm_src, N);
    scan_a<<<nbS, 256, 0, stream>>>(gHist, scanA, bsum, scanLen);
    scan_b<<<1, 1024, 0, stream>>>(bsum, boff, nbS);
    scan_c<<<nbS, 256, 0, stream>>>(scanA, boff, scanLen);
    scatter_coarse<<<NC, 256, 0, stream>>>(src, dst, scanA, packed, NB, NC, E);
    fine_sort<<<NB, 256, 0, stream>>>(packed, scanA, sorted, offsets, cntg, normd, NB, NC, N, E);

    // ---- layer 1 ----
    prep_x<<<(N * 32 + 255) / 256, 256, 0, stream>>>(x, norm_src, xh, N * 32);
    gemm_mfma<<<NP / 64, 256, 0, stream>>>(xh, Wt, h, N);
    aggregate_k<true><<<(N + 3) / 4, 256, 0, stream>>>((const __half*)h, sorted, offsets, cntg,
                                                       normd, norm_src, b1, nullptr,
                                                       (__half*)xh, N);

    // ---- layer 2 ----
    gemm_mfma<<<NP / 64, 256, 0, stream>>>(xh, Wt + HD * HD, h, N);
    aggregate_k<false><<<(N + 3) / 4, 256, 0, stream>>>((const __half*)h, sorted, offsets, cntg,
                                                        normd, nullptr, b2, out, nullptr, N);
}